// Round 5
// baseline (639.390 us; speedup 1.0000x reference)
//
#include <hip/hip_runtime.h>
#include <hip/hip_bf16.h>

namespace {

constexpr int Bn = 64, T1 = 128, T2 = 160, D = 768, M = 64;
constexpr int NTOT = T2 * M;     // 10240 (j-major, m-minor == output layout)
constexpr int BM = 128;          // i-tile (all of T1)
constexpr int BN = 128;          // jm-tile (2 j x 64 m)
constexpr int BK = 32;
constexpr int KSTEPS = D / BK;   // 24

typedef __bf16 bf16x8 __attribute__((ext_vector_type(8)));
typedef __bf16 bf16x4 __attribute__((ext_vector_type(4)));
typedef float  f32x4  __attribute__((ext_vector_type(4)));

__device__ __forceinline__ float fast_tanh(float x) {
  // tanh(x) = 1 - 2/(e^{2x}+1); exp overflow -> rcp(inf)=0 -> 1, underflow -> -1.
  float e = __expf(2.0f * x);
  return 1.0f - 2.0f * __builtin_amdgcn_rcpf(e + 1.0f);
}

__global__ void cvt_bf16(const float* __restrict__ x, __bf16* __restrict__ y, int n4) {
  int i = blockIdx.x * blockDim.x + threadIdx.x;
  if (i < n4) {
    f32x4 v = ((const f32x4*)x)[i];
    bf16x4 o;
    o[0] = (__bf16)v.x; o[1] = (__bf16)v.y; o[2] = (__bf16)v.z; o[3] = (__bf16)v.w;
    ((bf16x4*)y)[i] = o;
  }
}

// two products sharing the k-operand unpack: r0 = k*b0, r1 = k*b1 (bf16, fp32 math)
__device__ __forceinline__ void mul_bb2(uint4 a, uint4 b0, uint4 b1,
                                        bf16x8& r0, bf16x8& r1) {
  const unsigned hm = 0xffff0000u;
#define MPC_COMP(c, i0, i1)                                                   \
  {                                                                           \
    float al = __uint_as_float(a.c << 16), ah = __uint_as_float(a.c & hm);    \
    r0[i0] = (__bf16)(al * __uint_as_float(b0.c << 16));                      \
    r0[i1] = (__bf16)(ah * __uint_as_float(b0.c & hm));                       \
    r1[i0] = (__bf16)(al * __uint_as_float(b1.c << 16));                      \
    r1[i1] = (__bf16)(ah * __uint_as_float(b1.c & hm));                       \
  }
  MPC_COMP(x, 0, 1) MPC_COMP(y, 2, 3) MPC_COMP(z, 4, 5) MPC_COMP(w, 6, 7)
#undef MPC_COMP
}

// ---------------- fast path: PROVEN r0/r1 double-buffer main loop ----------
// (counted-vmcnt pipeline reverted: r4 measured it at 285us vs <=209us for
//  this structure -- the compiler inserts vmcnt(0) before ds_reads that alias
//  outstanding global_load_lds, exposing full load latency every step.)
// NEW vs r0/r1: LDS-staged coalesced epilogue. r4 counters showed
// WRITE_SIZE=606MB vs 335MB ideal (1.8x partial-line write amplification from
// 4B-stride-64B stores). Stage C through LDS, store float4 full lines.
__launch_bounds__(256, 4)
__global__ void mpcos_fast(const __bf16* __restrict__ v1b,
                           const __bf16* __restrict__ v2b,
                           const __bf16* __restrict__ kb,
                           float* __restrict__ out) {
  struct SmemT {
    union {
      struct { __bf16 A[2][BM * BK]; __bf16 B[2][BN * BK]; } g;  // 32 KB
      float c[32 * 132];                                          // 16.9 KB
    };
  };
  __shared__ SmemT sm;
  auto& Al = sm.g.A;
  auto& Bl = sm.g.B;

  const int t    = threadIdx.x;
  const int lane = t & 63;
  const int w    = t >> 6;
  const int bjm  = blockIdx.x;   // 0..79
  const int bb   = blockIdx.y;   // 0..63

  // ---- B staging mapping: thread -> (m = t>>2, 16B chunk c = t&3); kern slice
  // shared by both j-passes. Wave writes are contiguous 1 KB -> conflict-free.
  const int sm_ = t >> 2, sc = t & 3;
  const __bf16* kp   = kb + sm_ * D + sc * 8;
  const __bf16* v2p0 = v2b + ((size_t)(bb * T2 + bjm * 2)) * D + sc * 8;
  const __bf16* v2p1 = v2p0 + D;
  const int boff = sm_ * BK + ((sc ^ ((sm_ >> 1) & 3)) * 8);   // swizzled write

  // ---- A staging via global_load_lds (linear dest, pre-swizzled global src)
  const int arow = w * 32 + (lane >> 2);
  const int achk = (lane & 3) ^ ((lane >> 3) & 3);
  const __bf16* av1 = v1b + ((size_t)bb * T1 + arow) * D + achk * 8;
  const int adst = (w * 32) * BK;

  // ---- wave compute tile 64x64 ----
  const int wrow = (w & 1) * 64;
  const int wcol = (w >> 1) * 64;
  const int lr = lane & 15, lg = lane >> 4;
  const int swc = (lg ^ ((lr >> 1) & 3)) * 8;   // per-thread constant

  f32x4 acc[4][4] = {};

  // ---- prologue: stage step 0 into buffer 0 ----
  {
#pragma unroll
    for (int q = 0; q < 2; ++q)
      __builtin_amdgcn_global_load_lds(
          (const __attribute__((address_space(1))) void*)(av1 + q * 16 * D),
          (__attribute__((address_space(3))) void*)&Al[0][adst + q * 16 * BK],
          16, 0, 0);
    uint4 k0 = *(const uint4*)kp;
    uint4 u0 = *(const uint4*)v2p0;
    uint4 u1 = *(const uint4*)v2p1;
    bf16x8 r0, r1;
    mul_bb2(k0, u0, u1, r0, r1);
    *(bf16x8*)&Bl[0][boff]           = r0;
    *(bf16x8*)&Bl[0][64 * BK + boff] = r1;
    __syncthreads();
  }

  int cur = 0;
  for (int ks = 0; ks < KSTEPS; ++ks) {
    const int nxt = cur ^ 1;
    const bool more = (ks + 1 < KSTEPS);
    uint4 pk, pu0, pu1;
    if (more) {
      const int ko = (ks + 1) * BK;
      // async A -> other buffer; in flight across compute, drained at barrier
#pragma unroll
      for (int q = 0; q < 2; ++q)
        __builtin_amdgcn_global_load_lds(
            (const __attribute__((address_space(1))) void*)(av1 + ko + q * 16 * D),
            (__attribute__((address_space(3))) void*)&Al[nxt][adst + q * 16 * BK],
            16, 0, 0);
      // B register prefetch; consumed after compute
      pk  = *(const uint4*)(kp + ko);
      pu0 = *(const uint4*)(v2p0 + ko);
      pu1 = *(const uint4*)(v2p1 + ko);
    }

    // ---- compute step ks from buffer cur ----
    bf16x8 af[4], bfr[4];
#pragma unroll
    for (int ii = 0; ii < 4; ++ii)
      af[ii] = *(const bf16x8*)&Al[cur][(wrow + ii * 16 + lr) * BK + swc];
#pragma unroll
    for (int jj = 0; jj < 4; ++jj)
      bfr[jj] = *(const bf16x8*)&Bl[cur][(wcol + jj * 16 + lr) * BK + swc];
#pragma unroll
    for (int ii = 0; ii < 4; ++ii)
#pragma unroll
      for (int jj = 0; jj < 4; ++jj)
        acc[ii][jj] = __builtin_amdgcn_mfma_f32_16x16x32_bf16(
            af[ii], bfr[jj], acc[ii][jj], 0, 0, 0);

    if (more) {
      bf16x8 r0, r1;
      mul_bb2(pk, pu0, pu1, r0, r1);
      *(bf16x8*)&Bl[nxt][boff]           = r0;
      *(bf16x8*)&Bl[nxt][64 * BK + boff] = r1;
      __syncthreads();
    }
    cur = nxt;
  }

  // ---- epilogue: tanh + LDS-staged coalesced float4 stores ----
  // C/D frag: col = lane&15, row = (lane>>4)*4 + reg. 4 passes over ii; each
  // pass stages 32 "pass rows" x 128 cols f32 (stride 132 pads banks), then
  // 256 threads read back float4 and store full 128B lines (8 lanes/line).
  float* obase = out + (size_t)bb * T1 * NTOT + (size_t)bjm * BN;
  const int prow_base = (w & 1) * 16 + lg * 4;   // + r  -> 0..31
  const int pcol = wcol + lr;                    // + jj*16 -> 0..127
  const int rrow = t >> 5;                       // 0..7
  const int rc4  = t & 31;                       // float4 index in row
#pragma unroll
  for (int ii = 0; ii < 4; ++ii) {
    __syncthreads();   // pass 0: main-loop LDS reads done; later: readback done
#pragma unroll
    for (int jj = 0; jj < 4; ++jj)
#pragma unroll
      for (int r = 0; r < 4; ++r)
        sm.c[(prow_base + r) * 132 + pcol + jj * 16] = fast_tanh(acc[ii][jj][r]);
    __syncthreads();
#pragma unroll
    for (int rr = 0; rr < 4; ++rr) {
      const int pr = rr * 8 + rrow;                            // 0..31
      const int brow = ((pr >> 4) * 64) + ii * 16 + (pr & 15); // block row
      f32x4 v = *(const f32x4*)&sm.c[pr * 132 + rc4 * 4];
      *(f32x4*)&obase[(size_t)brow * NTOT + rc4 * 4] = v;
    }
  }
}

// ---------------- fallback (ws too small): proven round-2 single-buffer fp32 ----
__launch_bounds__(256, 3)
__global__ void mpcos_ref(const float* __restrict__ v1f,
                          const float* __restrict__ v2,
                          const float* __restrict__ kern,
                          float* __restrict__ out) {
  constexpr int BKr = 64;
  __shared__ __bf16 Alds[BM * BKr];
  __shared__ __bf16 Blds[BN * BKr];

  const int t = threadIdx.x, lane = t & 63, w = t >> 6;
  const int bjm = blockIdx.x, bb = blockIdx.y;
  const int srow = t >> 1, sc4 = (t & 1) * 4;
  const int sm = srow & (M - 1), sj = srow >> 6, ssw = srow & 7;
  const float* kp  = kern + sm * D + sc4 * 8;
  const float* v2p = v2 + ((size_t)(bb * T2 + bjm * 2 + sj)) * D + sc4 * 8;
  const float* v1p = v1f + ((size_t)bb * T1 + srow) * D + sc4 * 8;
  const int wrow = (w & 1) * 64, wcol = (w >> 1) * 64;
  const int lr = lane & 15, lg = lane >> 4, lr7 = lr & 7;

  f32x4 acc[4][4] = {};
  for (int ks = 0; ks < D / BKr; ++ks) {
    const int kb = ks * BKr;
    __syncthreads();
    const f32x4* a4 = (const f32x4*)(v1p + kb);
#pragma unroll
    for (int q = 0; q < 4; ++q) {
      f32x4 x0 = a4[2 * q], x1 = a4[2 * q + 1];
      bf16x8 wv;
      wv[0] = (__bf16)x0.x; wv[1] = (__bf16)x0.y; wv[2] = (__bf16)x0.z; wv[3] = (__bf16)x0.w;
      wv[4] = (__bf16)x1.x; wv[5] = (__bf16)x1.y; wv[6] = (__bf16)x1.z; wv[7] = (__bf16)x1.w;
      *(bf16x8*)&Alds[srow * BKr + (((sc4 + q) ^ ssw) * 8)] = wv;
    }
    const f32x4* k4 = (const f32x4*)(kp + kb);
    const f32x4* u4 = (const f32x4*)(v2p + kb);
#pragma unroll
    for (int q = 0; q < 4; ++q) {
      f32x4 a0 = k4[2 * q], a1 = k4[2 * q + 1];
      f32x4 b0 = u4[2 * q], b1 = u4[2 * q + 1];
      bf16x8 wv;
      wv[0] = (__bf16)(a0.x * b0.x); wv[1] = (__bf16)(a0.y * b0.y);
      wv[2] = (__bf16)(a0.z * b0.z); wv[3] = (__bf16)(a0.w * b0.w);
      wv[4] = (__bf16)(a1.x * b1.x); wv[5] = (__bf16)(a1.y * b1.y);
      wv[6] = (__bf16)(a1.z * b1.z); wv[7] = (__bf16)(a1.w * b1.w);
      *(bf16x8*)&Blds[srow * BKr + (((sc4 + q) ^ ssw) * 8)] = wv;
    }
    __syncthreads();
#pragma unroll
    for (int kk = 0; kk < BKr; kk += 32) {
      const int cb = kk >> 3;
      const int st = (((cb + lg) ^ lr7) * 8);
      bf16x8 af[4], bfr[4];
#pragma unroll
      for (int ii = 0; ii < 4; ++ii)
        af[ii] = *(const bf16x8*)&Alds[(wrow + ii * 16 + lr) * BKr + st];
#pragma unroll
      for (int jj = 0; jj < 4; ++jj)
        bfr[jj] = *(const bf16x8*)&Blds[(wcol + jj * 16 + lr) * BKr + st];
#pragma unroll
      for (int ii = 0; ii < 4; ++ii)
#pragma unroll
        for (int jj = 0; jj < 4; ++jj)
          acc[ii][jj] = __builtin_amdgcn_mfma_f32_16x16x32_bf16(
              af[ii], bfr[jj], acc[ii][jj], 0, 0, 0);
    }
  }
  float* obase = out + (size_t)bb * T1 * NTOT + (size_t)bjm * BN;
#pragma unroll
  for (int ii = 0; ii < 4; ++ii)
#pragma unroll
    for (int r = 0; r < 4; ++r) {
      const int row = wrow + ii * 16 + lg * 4 + r;
      float* orow = obase + (size_t)row * NTOT + wcol + lr;
#pragma unroll
      for (int jj = 0; jj < 4; ++jj)
        orow[jj * 16] = fast_tanh(acc[ii][jj][r]);
    }
}

}  // namespace

extern "C" void kernel_launch(void* const* d_in, const int* in_sizes, int n_in,
                              void* d_out, int out_size, void* d_ws, size_t ws_size,
                              hipStream_t stream) {
  const float* v1   = (const float*)d_in[0];
  const float* v2   = (const float*)d_in[1];
  const float* kern = (const float*)d_in[2];
  float* out = (float*)d_out;

  const size_t n_v1 = (size_t)Bn * T1 * D;   // 6,291,456
  const size_t n_v2 = (size_t)Bn * T2 * D;   // 7,864,320
  const size_t n_k  = (size_t)M * D;         // 49,152
  const size_t off_v2 = n_v1 * 2;            // bytes
  const size_t off_k  = off_v2 + n_v2 * 2;
  const size_t need   = off_k + n_k * 2;     // ~28.4 MB

  if (ws_size >= need) {
    __bf16* v1b = (__bf16*)((char*)d_ws);
    __bf16* v2b = (__bf16*)((char*)d_ws + off_v2);
    __bf16* kb  = (__bf16*)((char*)d_ws + off_k);
    cvt_bf16<<<(int)(n_v1 / 4 / 256), 256, 0, stream>>>(v1, v1b, (int)(n_v1 / 4));
    cvt_bf16<<<(int)(n_v2 / 4 / 256), 256, 0, stream>>>(v2, v2b, (int)(n_v2 / 4));
    cvt_bf16<<<(int)(n_k  / 4 / 256), 256, 0, stream>>>(kern, kb, (int)(n_k / 4));
    mpcos_fast<<<dim3(NTOT / BN, Bn), 256, 0, stream>>>(v1b, v2b, kb, out);
  } else {
    mpcos_ref<<<dim3(NTOT / BN, Bn), 256, 0, stream>>>(v1, v2, kern, out);
  }
}

// Round 7
// 506.222 us; speedup vs baseline: 1.2631x; 1.2631x over previous
//
#include <hip/hip_runtime.h>
#include <hip/hip_bf16.h>

namespace {

constexpr int Bn = 64, T1 = 128, T2 = 160, D = 768, M = 64;
constexpr int NTOT = T2 * M;     // 10240 (j-major, m-minor == output layout)
constexpr int BM = 128;          // i-tile (all of T1)
constexpr int BN = 128;          // jm-tile (2 j x 64 m)
constexpr int BK = 32;
constexpr int KSTEPS = D / BK;   // 24

typedef __bf16 bf16x8 __attribute__((ext_vector_type(8)));
typedef __bf16 bf16x4 __attribute__((ext_vector_type(4)));
typedef float  f32x4  __attribute__((ext_vector_type(4)));

__device__ __forceinline__ float fast_tanh(float x) {
  // tanh(x) = 1 - 2/(e^{2x}+1); exp overflow -> rcp(inf)=0 -> 1, underflow -> -1.
  float e = __expf(2.0f * x);
  return 1.0f - 2.0f * __builtin_amdgcn_rcpf(e + 1.0f);
}

__global__ void cvt_bf16(const float* __restrict__ x, __bf16* __restrict__ y, int n4) {
  int i = blockIdx.x * blockDim.x + threadIdx.x;
  if (i < n4) {
    f32x4 v = ((const f32x4*)x)[i];
    bf16x4 o;
    o[0] = (__bf16)v.x; o[1] = (__bf16)v.y; o[2] = (__bf16)v.z; o[3] = (__bf16)v.w;
    ((bf16x4*)y)[i] = o;
  }
}

// two products sharing the k-operand unpack: r0 = k*b0, r1 = k*b1 (bf16, fp32 math)
__device__ __forceinline__ void mul_bb2(uint4 a, uint4 b0, uint4 b1,
                                        bf16x8& r0, bf16x8& r1) {
  const unsigned hm = 0xffff0000u;
#define MPC_COMP(c, i0, i1)                                                   \
  {                                                                           \
    float al = __uint_as_float(a.c << 16), ah = __uint_as_float(a.c & hm);    \
    r0[i0] = (__bf16)(al * __uint_as_float(b0.c << 16));                      \
    r0[i1] = (__bf16)(ah * __uint_as_float(b0.c & hm));                       \
    r1[i0] = (__bf16)(al * __uint_as_float(b1.c << 16));                      \
    r1[i1] = (__bf16)(ah * __uint_as_float(b1.c & hm));                       \
  }
  MPC_COMP(x, 0, 1) MPC_COMP(y, 2, 3) MPC_COMP(z, 4, 5) MPC_COMP(w, 6, 7)
#undef MPC_COMP
}

// ---------------- fast path: PROVEN r0/r1 double-buffer main loop ----------
// History: r4 counted-vmcnt pipeline = 285us (compiler vmcnt(0) before
// aliasing ds_reads) -> reverted. r5 LDS-staged epilogue = 351us, bank
// conflicts 0 -> 1.26e8 (mechanism unexplained; fix abandoned) but proved
// WRITE_SIZE 606MB -> 335MB ideal is reachable. r6 = this kernel, infra
// flake ("container failed twice"), no verdict -> resubmit unchanged.
// MFMA OPERAND SWAP: mfma(bfr, af, acc) transposes the C/D mapping so each
// lane holds 4 CONSECUTIVE jm values at fixed output row i -> epilogue is
// one f32x4 store per subtile; a store instruction covers 16 rows x 64B
// contiguous, adjacent jj completes each 128B line. Ideal writes, no LDS
// epilogue, no bank conflicts. Staging and fragment reads byte-identical
// to r0/r1 (A and B fragments share the same per-lane encoding).
__launch_bounds__(256, 4)
__global__ void mpcos_fast(const __bf16* __restrict__ v1b,
                           const __bf16* __restrict__ v2b,
                           const __bf16* __restrict__ kb,
                           float* __restrict__ out) {
  __shared__ __bf16 Al[2][BM * BK];  // 2 x 8 KB
  __shared__ __bf16 Bl[2][BN * BK];  // 2 x 8 KB

  const int t    = threadIdx.x;
  const int lane = t & 63;
  const int w    = t >> 6;
  const int bjm  = blockIdx.x;   // 0..79
  const int bb   = blockIdx.y;   // 0..63

  // ---- B staging mapping: thread -> (m = t>>2, 16B chunk c = t&3); kern slice
  // shared by both j-passes. Wave writes are contiguous 1 KB -> conflict-free.
  const int sm = t >> 2, sc = t & 3;
  const __bf16* kp   = kb + sm * D + sc * 8;
  const __bf16* v2p0 = v2b + ((size_t)(bb * T2 + bjm * 2)) * D + sc * 8;
  const __bf16* v2p1 = v2p0 + D;
  const int boff = sm * BK + ((sc ^ ((sm >> 1) & 3)) * 8);   // swizzled write

  // ---- A staging via global_load_lds (linear dest, pre-swizzled global src)
  const int arow = w * 32 + (lane >> 2);
  const int achk = (lane & 3) ^ ((lane >> 3) & 3);
  const __bf16* av1 = v1b + ((size_t)bb * T1 + arow) * D + achk * 8;
  const int adst = (w * 32) * BK;

  // ---- wave compute tile 64x64 ----
  const int wrow = (w & 1) * 64;
  const int wcol = (w >> 1) * 64;
  const int lr = lane & 15, lg = lane >> 4;
  const int swc = (lg ^ ((lr >> 1) & 3)) * 8;   // per-thread constant

  f32x4 acc[4][4] = {};   // acc[jj][ii]: jj = jm-subtile (A-op), ii = i-subtile

  // ---- prologue: stage step 0 into buffer 0 ----
  {
#pragma unroll
    for (int q = 0; q < 2; ++q)
      __builtin_amdgcn_global_load_lds(
          (const __attribute__((address_space(1))) void*)(av1 + q * 16 * D),
          (__attribute__((address_space(3))) void*)&Al[0][adst + q * 16 * BK],
          16, 0, 0);
    uint4 k0 = *(const uint4*)kp;
    uint4 u0 = *(const uint4*)v2p0;
    uint4 u1 = *(const uint4*)v2p1;
    bf16x8 r0, r1;
    mul_bb2(k0, u0, u1, r0, r1);
    *(bf16x8*)&Bl[0][boff]           = r0;
    *(bf16x8*)&Bl[0][64 * BK + boff] = r1;
    __syncthreads();
  }

  int cur = 0;
  for (int ks = 0; ks < KSTEPS; ++ks) {
    const int nxt = cur ^ 1;
    const bool more = (ks + 1 < KSTEPS);
    uint4 pk, pu0, pu1;
    if (more) {
      const int ko = (ks + 1) * BK;
      // async A -> other buffer; in flight across compute, drained at barrier
#pragma unroll
      for (int q = 0; q < 2; ++q)
        __builtin_amdgcn_global_load_lds(
            (const __attribute__((address_space(1))) void*)(av1 + ko + q * 16 * D),
            (__attribute__((address_space(3))) void*)&Al[nxt][adst + q * 16 * BK],
            16, 0, 0);
      // B register prefetch; consumed after compute
      pk  = *(const uint4*)(kp + ko);
      pu0 = *(const uint4*)(v2p0 + ko);
      pu1 = *(const uint4*)(v2p1 + ko);
    }

    // ---- compute step ks from buffer cur (operand-swapped MFMA) ----
    bf16x8 af[4], bfr[4];
#pragma unroll
    for (int ii = 0; ii < 4; ++ii)
      af[ii] = *(const bf16x8*)&Al[cur][(wrow + ii * 16 + lr) * BK + swc];
#pragma unroll
    for (int jj = 0; jj < 4; ++jj)
      bfr[jj] = *(const bf16x8*)&Bl[cur][(wcol + jj * 16 + lr) * BK + swc];
#pragma unroll
    for (int jj = 0; jj < 4; ++jj)
#pragma unroll
      for (int ii = 0; ii < 4; ++ii)
        acc[jj][ii] = __builtin_amdgcn_mfma_f32_16x16x32_bf16(
            bfr[jj], af[ii], acc[jj][ii], 0, 0, 0);

    if (more) {
      bf16x8 r0, r1;
      mul_bb2(pk, pu0, pu1, r0, r1);
      *(bf16x8*)&Bl[nxt][boff]           = r0;
      *(bf16x8*)&Bl[nxt][64 * BK + boff] = r1;
      __syncthreads();
    }
    cur = nxt;
  }

  // ---- epilogue: tanh + vectorized store ----
  // Swapped C/D: lane holds C[jm_local = lg*4 + r][i_local = lr] for subtile
  // (jj, ii) -> output row i = wrow + ii*16 + lr, cols jm = wcol + jj*16 +
  // lg*4 + (0..3): one f32x4 per subtile, 64B contiguous per 16-lane group.
  float* obase = out + (size_t)bb * T1 * NTOT + (size_t)bjm * BN;
#pragma unroll
  for (int jj = 0; jj < 4; ++jj) {
#pragma unroll
    for (int ii = 0; ii < 4; ++ii) {
      const int row = wrow + ii * 16 + lr;
      const int col = wcol + jj * 16 + lg * 4;
      f32x4 v;
#pragma unroll
      for (int r = 0; r < 4; ++r) v[r] = fast_tanh(acc[jj][ii][r]);
      *(f32x4*)&obase[(size_t)row * NTOT + col] = v;
    }
  }
}

// ---------------- fallback (ws too small): proven round-2 single-buffer fp32 ----
__launch_bounds__(256, 3)
__global__ void mpcos_ref(const float* __restrict__ v1f,
                          const float* __restrict__ v2,
                          const float* __restrict__ kern,
                          float* __restrict__ out) {
  constexpr int BKr = 64;
  __shared__ __bf16 Alds[BM * BKr];
  __shared__ __bf16 Blds[BN * BKr];

  const int t = threadIdx.x, lane = t & 63, w = t >> 6;
  const int bjm = blockIdx.x, bb = blockIdx.y;
  const int srow = t >> 1, sc4 = (t & 1) * 4;
  const int sm = srow & (M - 1), sj = srow >> 6, ssw = srow & 7;
  const float* kp  = kern + sm * D + sc4 * 8;
  const float* v2p = v2 + ((size_t)(bb * T2 + bjm * 2 + sj)) * D + sc4 * 8;
  const float* v1p = v1f + ((size_t)bb * T1 + srow) * D + sc4 * 8;
  const int wrow = (w & 1) * 64, wcol = (w >> 1) * 64;
  const int lr = lane & 15, lg = lane >> 4, lr7 = lr & 7;

  f32x4 acc[4][4] = {};
  for (int ks = 0; ks < D / BKr; ++ks) {
    const int kb = ks * BKr;
    __syncthreads();
    const f32x4* a4 = (const f32x4*)(v1p + kb);
#pragma unroll
    for (int q = 0; q < 4; ++q) {
      f32x4 x0 = a4[2 * q], x1 = a4[2 * q + 1];
      bf16x8 wv;
      wv[0] = (__bf16)x0.x; wv[1] = (__bf16)x0.y; wv[2] = (__bf16)x0.z; wv[3] = (__bf16)x0.w;
      wv[4] = (__bf16)x1.x; wv[5] = (__bf16)x1.y; wv[6] = (__bf16)x1.z; wv[7] = (__bf16)x1.w;
      *(bf16x8*)&Alds[srow * BKr + (((sc4 + q) ^ ssw) * 8)] = wv;
    }
    const f32x4* k4 = (const f32x4*)(kp + kb);
    const f32x4* u4 = (const f32x4*)(v2p + kb);
#pragma unroll
    for (int q = 0; q < 4; ++q) {
      f32x4 a0 = k4[2 * q], a1 = k4[2 * q + 1];
      f32x4 b0 = u4[2 * q], b1 = u4[2 * q + 1];
      bf16x8 wv;
      wv[0] = (__bf16)(a0.x * b0.x); wv[1] = (__bf16)(a0.y * b0.y);
      wv[2] = (__bf16)(a0.z * b0.z); wv[3] = (__bf16)(a0.w * b0.w);
      wv[4] = (__bf16)(a1.x * b1.x); wv[5] = (__bf16)(a1.y * b1.y);
      wv[6] = (__bf16)(a1.z * b1.z); wv[7] = (__bf16)(a1.w * b1.w);
      *(bf16x8*)&Blds[srow * BKr + (((sc4 + q) ^ ssw) * 8)] = wv;
    }
    __syncthreads();
#pragma unroll
    for (int kk = 0; kk < BKr; kk += 32) {
      const int cb = kk >> 3;
      const int st = (((cb + lg) ^ lr7) * 8);
      bf16x8 af[4], bfr[4];
#pragma unroll
      for (int ii = 0; ii < 4; ++ii)
        af[ii] = *(const bf16x8*)&Alds[(wrow + ii * 16 + lr) * BKr + st];
#pragma unroll
      for (int jj = 0; jj < 4; ++jj)
        bfr[jj] = *(const bf16x8*)&Blds[(wcol + jj * 16 + lr) * BKr + st];
#pragma unroll
      for (int ii = 0; ii < 4; ++ii)
#pragma unroll
        for (int jj = 0; jj < 4; ++jj)
          acc[ii][jj] = __builtin_amdgcn_mfma_f32_16x16x32_bf16(
              af[ii], bfr[jj], acc[ii][jj], 0, 0, 0);
    }
  }
  float* obase = out + (size_t)bb * T1 * NTOT + (size_t)bjm * BN;
#pragma unroll
  for (int ii = 0; ii < 4; ++ii)
#pragma unroll
    for (int r = 0; r < 4; ++r) {
      const int row = wrow + ii * 16 + lg * 4 + r;
      float* orow = obase + (size_t)row * NTOT + wcol + lr;
#pragma unroll
      for (int jj = 0; jj < 4; ++jj)
        orow[jj * 16] = fast_tanh(acc[ii][jj][r]);
    }
}

}  // namespace

extern "C" void kernel_launch(void* const* d_in, const int* in_sizes, int n_in,
                              void* d_out, int out_size, void* d_ws, size_t ws_size,
                              hipStream_t stream) {
  const float* v1   = (const float*)d_in[0];
  const float* v2   = (const float*)d_in[1];
  const float* kern = (const float*)d_in[2];
  float* out = (float*)d_out;

  const size_t n_v1 = (size_t)Bn * T1 * D;   // 6,291,456
  const size_t n_v2 = (size_t)Bn * T2 * D;   // 7,864,320
  const size_t n_k  = (size_t)M * D;         // 49,152
  const size_t off_v2 = n_v1 * 2;            // bytes
  const size_t off_k  = off_v2 + n_v2 * 2;
  const size_t need   = off_k + n_k * 2;     // ~28.4 MB

  if (ws_size >= need) {
    __bf16* v1b = (__bf16*)((char*)d_ws);
    __bf16* v2b = (__bf16*)((char*)d_ws + off_v2);
    __bf16* kb  = (__bf16*)((char*)d_ws + off_k);
    cvt_bf16<<<(int)(n_v1 / 4 / 256), 256, 0, stream>>>(v1, v1b, (int)(n_v1 / 4));
    cvt_bf16<<<(int)(n_v2 / 4 / 256), 256, 0, stream>>>(v2, v2b, (int)(n_v2 / 4));
    cvt_bf16<<<(int)(n_k  / 4 / 256), 256, 0, stream>>>(kern, kb, (int)(n_k / 4));
    mpcos_fast<<<dim3(NTOT / BN, Bn), 256, 0, stream>>>(v1b, v2b, kb, out);
  } else {
    mpcos_ref<<<dim3(NTOT / BN, Bn), 256, 0, stream>>>(v1, v2, kern, out);
  }
}